// Round 5
// baseline (1153.469 us; speedup 1.0000x reference)
//
#include <hip/hip_runtime.h>

#define TT 60
#define EC 384

typedef __attribute__((ext_vector_type(8))) short short8v;
typedef __attribute__((ext_vector_type(16))) float f32x16;

__device__ __forceinline__ unsigned short f2bf(float f) {
  unsigned u = __float_as_uint(f);
  u += 0x7fff + ((u >> 16) & 1);
  return (unsigned short)(u >> 16);
}
__device__ __forceinline__ float bf2f(unsigned short h) {
  return __uint_as_float(((unsigned)h) << 16);
}
__device__ __forceinline__ float sigmoidf_(float x) {
  return 1.f / (1.f + __expf(-x));
}
__device__ __forceinline__ float tanhf_(float x) {
  x = fminf(fmaxf(x, -15.f), 15.f);
  float e = __expf(-2.f * x);
  return (1.f - e) / (1.f + e);
}

#define MF(a, b, c) __builtin_amdgcn_mfma_f32_32x32x16_bf16(a, b, c, 0, 0, 0)

// ---- weight packing: W~[r~][k] -> lane-linear fragment order, split hi/lo bf16.
// (verified in rounds 2/3)
__global__ void pack_w(const float* __restrict__ Wih, const float* __restrict__ Whh,
                       int Kx, int ncW, unsigned short* __restrict__ dst) {
  int id = blockIdx.x * 256 + threadIdx.x;
  int total = 16 * ncW * 512;
  if (id >= total) return;
  int j = id & 7, lane = (id >> 3) & 63, c = (id >> 9) % ncW, tr = id / (512 * ncW);
  int rw = lane & 31, q = rw >> 3, dl = rw & 7;
  int R = q * 128 + tr * 8 + dl;
  int k = c * 16 + (lane >> 5) * 8 + j;
  float v = (k < Kx) ? Wih[(size_t)R * Kx + k] : Whh[(size_t)R * 128 + (k - Kx)];
  unsigned short hi = f2bf(v);
  unsigned short lo = f2bf(v - bf2f(hi));
  dst[((size_t)(tr * ncW + c) * 2 + 0) * 512 + lane * 8 + j] = hi;
  dst[((size_t)(tr * ncW + c) * 2 + 1) * 512 + lane * 8 + j] = lo;
}

__global__ void pack_bias(const float* b0i, const float* b0h, const float* b1i, const float* b1h,
                          float* __restrict__ dst) {
  int tid = blockIdx.x * 256 + threadIdx.x;
  if (tid >= 1024) return;
  int l = tid >> 9, rr = tid & 511;
  int tr = rr >> 5, rw = rr & 31, q = rw >> 3, dl = rw & 7;
  int R = q * 128 + tr * 8 + dl;
  dst[tid] = l ? (b1i[R] + b1h[R]) : (b0i[R] + b0h[R]);
}

struct NArgs {
  const unsigned short* w0f;
  const unsigned short* w1f;
  const float* x;
  const float* biasP;
  float* h1f32;
};

// Node-parallel fused 2-layer LSTM: block = 32 nodes x ALL 512 gate-rows.
// 8 waves x 2 row-tiles (trA=w, trB=w+8). h0/h1 in LDS (fragment-linear,
// conflict-free b128 reads); c-state in registers; weights streamed from L2.
// 60 steps, 3 __syncthreads()/step, ONE launch, no grid sync.
__global__ __launch_bounds__(512, 2) void lstm_node(NArgs P) {
  __shared__ unsigned short hl0[8 * 1024];   // [chunk][hi/lo][512]
  __shared__ unsigned short hl1[8 * 1024];
  const int tid = threadIdx.x;
  const int lane = tid & 63;
  const int wv = tid >> 6;                   // 0..7
  const int trA = wv, trB = wv + 8;
  const int lanelo = lane & 31, lanehi = lane >> 5;
  const int nb = blockIdx.x * 32;
  const int node = nb + lanelo;              // 125*32 = 4000 exact

  const unsigned short* w0A = P.w0f + (size_t)(trA * 9) * 1024 + lane * 8;
  const unsigned short* w0B = P.w0f + (size_t)(trB * 9) * 1024 + lane * 8;
  const unsigned short* w1A = P.w1f + (size_t)(trA * 16) * 1024 + lane * 8;
  const unsigned short* w1B = P.w1f + (size_t)(trB * 16) * 1024 + lane * 8;

  float c0A[4] = {0,0,0,0}, c0B[4] = {0,0,0,0};
  float c1A[4] = {0,0,0,0}, c1B[4] = {0,0,0,0};

  // bias fragments resident in registers
  f32x16 bv0A, bv0B, bv1A, bv1B;
  #pragma unroll
  for (int r = 0; r < 16; r++) {
    int ro = (r & 3) + 8 * (r >> 2) + 4 * lanehi;
    bv0A[r] = P.biasP[trA * 32 + ro];
    bv0B[r] = P.biasP[trB * 32 + ro];
    bv1A[r] = P.biasP[512 + trA * 32 + ro];
    bv1B[r] = P.biasP[512 + trB * 32 + ro];
  }

  // 8-chunk run: W streamed (2-deep rolling prefetch), B from LDS.
  auto run8 = [&](const unsigned short* pwA, const unsigned short* pwB,
                  const unsigned short* lb, f32x16& aA, f32x16& aB) {
    const unsigned short* lbp = lb + lane * 8;
    short8v wAh0 = *(const short8v*)pwA;
    short8v wAl0 = *(const short8v*)(pwA + 512);
    short8v wBh0 = *(const short8v*)pwB;
    short8v wBl0 = *(const short8v*)(pwB + 512);
    short8v bh0 = *(const short8v*)lbp;
    short8v bl0 = *(const short8v*)(lbp + 512);
    #pragma unroll
    for (int c = 0; c < 8; c += 2) {
      short8v wAh1, wAl1, wBh1, wBl1, bh1, bl1;
      {
        const unsigned short* qA = pwA + (c + 1) * 1024;
        const unsigned short* qB = pwB + (c + 1) * 1024;
        wAh1 = *(const short8v*)qA; wAl1 = *(const short8v*)(qA + 512);
        wBh1 = *(const short8v*)qB; wBl1 = *(const short8v*)(qB + 512);
        bh1 = *(const short8v*)(lbp + (c + 1) * 1024);
        bl1 = *(const short8v*)(lbp + (c + 1) * 1024 + 512);
      }
      aA = MF(wAh0, bh0, aA); aB = MF(wBh0, bh0, aB);
      aA = MF(wAh0, bl0, aA); aB = MF(wBh0, bl0, aB);
      aA = MF(wAl0, bh0, aA); aB = MF(wBl0, bh0, aB);
      if (c + 2 < 8) {
        const unsigned short* qA = pwA + (c + 2) * 1024;
        const unsigned short* qB = pwB + (c + 2) * 1024;
        wAh0 = *(const short8v*)qA; wAl0 = *(const short8v*)(qA + 512);
        wBh0 = *(const short8v*)qB; wBl0 = *(const short8v*)(qB + 512);
        bh0 = *(const short8v*)(lbp + (c + 2) * 1024);
        bl0 = *(const short8v*)(lbp + (c + 2) * 1024 + 512);
      }
      aA = MF(wAh1, bh1, aA); aB = MF(wBh1, bh1, aB);
      aA = MF(wAh1, bl1, aA); aB = MF(wBh1, bl1, aB);
      aA = MF(wAl1, bh1, aA); aB = MF(wBl1, bh1, aB);
    }
  };

  auto epi = [&](int tr, const f32x16& acc, float (&cr)[4], unsigned short* lbase, bool wf32) {
    const int D0 = tr * 8 + 4 * lanehi;
    float ho[4];
    #pragma unroll
    for (int dl = 0; dl < 4; dl++) {
      float i_ = sigmoidf_(acc[dl]);
      float f_ = sigmoidf_(acc[4 + dl]);
      float g_ = tanhf_(acc[8 + dl]);
      float o_ = sigmoidf_(acc[12 + dl]);
      float cn = f_ * cr[dl] + i_ * g_;
      cr[dl] = cn;
      ho[dl] = o_ * tanhf_(cn);
    }
    if (wf32)
      *(float4*)(P.h1f32 + (size_t)node * 128 + D0) = make_float4(ho[0], ho[1], ho[2], ho[3]);
    unsigned short* dst = lbase + (tr >> 1) * 1024 + (lanelo + 32 * (tr & 1)) * 8 + 4 * lanehi;
    ushort4 hs, ls;
    hs.x = f2bf(ho[0]); ls.x = f2bf(ho[0] - bf2f(hs.x));
    hs.y = f2bf(ho[1]); ls.y = f2bf(ho[1] - bf2f(hs.y));
    hs.z = f2bf(ho[2]); ls.z = f2bf(ho[2] - bf2f(hs.z));
    hs.w = f2bf(ho[3]); ls.w = f2bf(ho[3] - bf2f(hs.w));
    *(ushort4*)dst = hs;
    *(ushort4*)(dst + 512) = ls;
  };

  for (int t = 0; t < TT; t++) {
    // ---- layer 0: gates = W0~ . [x_t | h0_{t-1}]
    f32x16 aA = bv0A, aB = bv0B;
    {
      const float* xp = P.x + ((size_t)node * TT + t) * 16 + lanehi * 8;
      float4 f0v = *(const float4*)xp, f1v = *(const float4*)(xp + 4);
      float fv[8] = {f0v.x, f0v.y, f0v.z, f0v.w, f1v.x, f1v.y, f1v.z, f1v.w};
      union { short8v v; unsigned short u[8]; } XH, XL;
      #pragma unroll
      for (int e = 0; e < 8; e++) {
        unsigned short h = f2bf(fv[e]);
        XH.u[e] = h; XL.u[e] = f2bf(fv[e] - bf2f(h));
      }
      short8v wAh = *(const short8v*)w0A, wAl = *(const short8v*)(w0A + 512);
      short8v wBh = *(const short8v*)w0B, wBl = *(const short8v*)(w0B + 512);
      aA = MF(wAh, XH.v, aA); aB = MF(wBh, XH.v, aB);
      aA = MF(wAh, XL.v, aA); aB = MF(wBh, XL.v, aB);
      aA = MF(wAl, XH.v, aA); aB = MF(wBl, XH.v, aB);
    }
    if (t > 0) run8(w0A + 1024, w0B + 1024, hl0, aA, aB);
    __syncthreads();                       // S1: all hl0 reads done
    epi(trA, aA, c0A, hl0, false);
    epi(trB, aB, c0B, hl0, false);
    __syncthreads();                       // S2: hl0 = h0(t) ready

    // ---- layer 1: gates = W1~ . [h0_t | h1_{t-1}]
    aA = bv1A; aB = bv1B;
    run8(w1A, w1B, hl0, aA, aB);
    if (t > 0) run8(w1A + 8 * 1024, w1B + 8 * 1024, hl1, aA, aB);
    __syncthreads();                       // S3: all hl0/hl1 reads done
    const bool last = (t == TT - 1);
    epi(trA, aA, c1A, hl1, last);
    epi(trB, aB, c1B, hl1, last);
    // epi writes hl1; next readers are after S1/S2 of t+1 -> safe
  }
}

// ---------------- attention ----------------
__global__ void attn_prep(const float* __restrict__ Wt, const float* __restrict__ bt,
                          const float* __restrict__ a, float* __restrict__ uv) {
  int k = threadIdx.x;
  float us = 0.f, ud = 0.f;
  for (int j = 0; j < 128; j++) {
    float w = Wt[j * 128 + k];
    us += a[j] * w;
    ud += a[128 + j] * w;
  }
  uv[k] = us; uv[128 + k] = ud;
  __shared__ float red[128];
  red[k] = bt[k] * a[k];
  __syncthreads();
  for (int st = 64; st; st >>= 1) { if (k < st) red[k] += red[k + st]; __syncthreads(); }
  if (k == 0) uv[256] = red[0];
  __syncthreads();
  red[k] = bt[k] * a[128 + k];
  __syncthreads();
  for (int st = 64; st; st >>= 1) { if (k < st) red[k] += red[k + st]; __syncthreads(); }
  if (k == 0) uv[257] = red[0];
}

__global__ void attn_scores(const float* __restrict__ hid, const float* __restrict__ uv,
                            float* __restrict__ ssrc, float* __restrict__ sdst, int N) {
  int wave = threadIdx.x >> 6, lane = threadIdx.x & 63;
  int i = blockIdx.x * 4 + wave;
  if (i >= N) return;
  float h0 = hid[(long)i * 128 + lane], h1 = hid[(long)i * 128 + 64 + lane];
  float us = h0 * uv[lane] + h1 * uv[64 + lane];
  float ud = h0 * uv[128 + lane] + h1 * uv[192 + lane];
  for (int off = 32; off; off >>= 1) { us += __shfl_down(us, off); ud += __shfl_down(ud, off); }
  if (lane == 0) { ssrc[i] = us + uv[256]; sdst[i] = ud + uv[257]; }
}

__global__ void colsum_part(const float* __restrict__ hid, float* __restrict__ part, int N) {
  int d = threadIdx.x, b = blockIdx.x;
  int per = (N + 31) / 32;
  int n0 = b * per, n1 = min(N, n0 + per);
  float s = 0.f;
  for (int n = n0; n < n1; n++) s += hid[(long)n * 128 + d];
  part[b * 128 + d] = s;
}
__global__ void colsum_fold(const float* __restrict__ part, float* __restrict__ csum) {
  int d = threadIdx.x;
  float s = 0.f;
  for (int b = 0; b < 32; b++) s += part[b * 128 + d];
  csum[d] = s;
}

// One-time adjacency scan -> per-row edge lists (adj identical both rounds).
__global__ __launch_bounds__(256) void build_csr(const float* __restrict__ adj, int* __restrict__ deg,
                                                 int* __restrict__ eidx, int N) {
  const int i = blockIdx.x, tid = threadIdx.x;
  __shared__ int cnt;
  if (tid == 0) cnt = 0;
  __syncthreads();
  const float4* arow = (const float4*)(adj + (size_t)i * N);
  for (int v = tid; v < N / 4; v += 256) {
    float4 a = arow[v];
    int j = 4 * v;
    if (a.x != 0.f) { int k = atomicAdd(&cnt, 1); if (k < EC) eidx[(size_t)i * EC + k] = j; }
    if (a.y != 0.f) { int k = atomicAdd(&cnt, 1); if (k < EC) eidx[(size_t)i * EC + k] = j + 1; }
    if (a.z != 0.f) { int k = atomicAdd(&cnt, 1); if (k < EC) eidx[(size_t)i * EC + k] = j + 2; }
    if (a.w != 0.f) { int k = atomicAdd(&cnt, 1); if (k < EC) eidx[(size_t)i * EC + k] = j + 3; }
  }
  __syncthreads();
  if (tid == 0) deg[i] = cnt;
}

// Sparse masked-softmax + gather over precomputed edges.
__global__ __launch_bounds__(256) void attn_apply(const int* __restrict__ deg, const int* __restrict__ eidx,
    const float* __restrict__ adj, const float* __restrict__ ssrc, const float* __restrict__ sdst,
    const float* __restrict__ hid, const float* __restrict__ csum, float* __restrict__ hout, int N) {
  const int i = blockIdx.x, tid = threadIdx.x;
  __shared__ float sw[EC];
  __shared__ int sidx[EC];
  __shared__ float red[256];
  const int cnt = deg[i];
  const float sd = sdst[i];
  const bool fits = (cnt <= EC);
  float m = 0.f;
  if (fits) {
    for (int k = tid; k < cnt; k += 256) {
      int j = eidx[(size_t)i * EC + k];
      float s = sd + ssrc[j];
      s = s > 0.f ? s : 0.01f * s;
      sidx[k] = j; sw[k] = s;
      m = fmaxf(m, s);
    }
  } else {
    const float* arow = adj + (size_t)i * N;
    for (int j = tid; j < N; j += 256)
      if (arow[j] != 0.f) { float s = sd + ssrc[j]; s = s > 0.f ? s : 0.01f * s; m = fmaxf(m, s); }
  }
  red[tid] = m; __syncthreads();
  for (int st = 128; st; st >>= 1) { if (tid < st) red[tid] = fmaxf(red[tid], red[tid + st]); __syncthreads(); }
  m = red[0];
  const float e0 = __expf(-m);
  float dc = 0.f;
  if (fits) {
    for (int k = tid; k < cnt; k += 256) { float w2 = __expf(sw[k] - m) - e0; sw[k] = w2; dc += w2; }
  } else {
    const float* arow = adj + (size_t)i * N;
    for (int j = tid; j < N; j += 256)
      if (arow[j] != 0.f) { float s = sd + ssrc[j]; s = s > 0.f ? s : 0.01f * s; dc += __expf(s - m) - e0; }
  }
  __syncthreads();
  red[tid] = dc; __syncthreads();
  for (int st = 128; st; st >>= 1) { if (tid < st) red[tid] += red[tid + st]; __syncthreads(); }
  const float inv = 1.f / ((float)N * e0 + red[0]);
  const int d = tid & 127, g = tid >> 7;
  float acc = 0.f;
  if (fits) {
    #pragma unroll 4
    for (int k = g; k < cnt; k += 2)
      acc += sw[k] * hid[(size_t)sidx[k] * 128 + d];
  } else {
    const float* arow = adj + (size_t)i * N;
    for (int j = g; j < N; j += 2) {
      if (arow[j] != 0.f) {
        float s = sd + ssrc[j]; s = s > 0.f ? s : 0.01f * s;
        acc += (__expf(s - m) - e0) * hid[(size_t)j * 128 + d];
      }
    }
  }
  __syncthreads();
  red[tid] = acc; __syncthreads();
  if (g == 0) {
    float tot = e0 * csum[d] + red[tid] + red[128 + tid];
    hout[(size_t)i * 128 + d] = tot * inv + hid[(size_t)i * 128 + d];
  }
}

// out[n] = Wout . leaky(hid[n] @ Wfc^T + bfc) + bout
__global__ __launch_bounds__(256) void head_kernel(const float* __restrict__ hid, const float* __restrict__ Wfc,
                            const float* __restrict__ bfc, const float* __restrict__ Wout,
                            const float* __restrict__ bout, float* __restrict__ out, int N) {
  __shared__ float wT[64 * 128];   // [k][j]
  __shared__ float hL[32 * 64];    // [r][k]
  const int tid = threadIdx.x;
  const int row0 = blockIdx.x * 32;
  const int js = tid & 31, r0 = (tid >> 5) * 4;

  float fc[4][4];
  #pragma unroll
  for (int ri = 0; ri < 4; ri++)
    #pragma unroll
    for (int ji = 0; ji < 4; ji++) fc[ri][ji] = 0.f;

  for (int half = 0; half < 2; half++) {
    const int k0 = half * 64;
    __syncthreads();
    {
      int jj = tid & 127, kg = (tid >> 7) * 32;
      for (int kk = 0; kk < 32; kk++)
        wT[(kg + kk) * 128 + jj] = Wfc[(size_t)jj * 128 + k0 + kg + kk];
      int rr = tid >> 3, ks = (tid & 7) * 8;
      float4 a = *(const float4*)(hid + (size_t)(row0 + rr) * 128 + k0 + ks);
      float4 b = *(const float4*)(hid + (size_t)(row0 + rr) * 128 + k0 + ks + 4);
      *(float4*)(hL + rr * 64 + ks) = a;
      *(float4*)(hL + rr * 64 + ks + 4) = b;
    }
    __syncthreads();
    #pragma unroll 4
    for (int k = 0; k < 64; k++) {
      float h0 = hL[(r0 + 0) * 64 + k];
      float h1 = hL[(r0 + 1) * 64 + k];
      float h2 = hL[(r0 + 2) * 64 + k];
      float h3 = hL[(r0 + 3) * 64 + k];
      #pragma unroll
      for (int ji = 0; ji < 4; ji++) {
        float wv2 = wT[k * 128 + js + 32 * ji];
        fc[0][ji] += h0 * wv2;
        fc[1][ji] += h1 * wv2;
        fc[2][ji] += h2 * wv2;
        fc[3][ji] += h3 * wv2;
      }
    }
  }

  float wo[4], bj[4];
  #pragma unroll
  for (int ji = 0; ji < 4; ji++) { wo[ji] = Wout[js + 32 * ji]; bj[ji] = bfc[js + 32 * ji]; }
  float bo = bout[0];
  #pragma unroll
  for (int ri = 0; ri < 4; ri++) {
    float v = 0.f;
    #pragma unroll
    for (int ji = 0; ji < 4; ji++) {
      float g = fc[ri][ji] + bj[ji];
      g = g > 0.f ? g : 0.01f * g;
      v += wo[ji] * g;
    }
    v += __shfl_down(v, 16);
    v += __shfl_down(v, 8);
    v += __shfl_down(v, 4);
    v += __shfl_down(v, 2);
    v += __shfl_down(v, 1);
    if (js == 0) out[row0 + r0 + ri] = v + bo;
  }
}

extern "C" void kernel_launch(void* const* d_in, const int* in_sizes, int n_in,
                              void* d_out, int out_size, void* d_ws, size_t ws_size,
                              hipStream_t stream) {
  const float* x    = (const float*)d_in[0];
  const float* adj  = (const float*)d_in[1];
  const float* Wih0 = (const float*)d_in[2];
  const float* Whh0 = (const float*)d_in[3];
  const float* bih0 = (const float*)d_in[4];
  const float* bhh0 = (const float*)d_in[5];
  const float* Wih1 = (const float*)d_in[6];
  const float* Whh1 = (const float*)d_in[7];
  const float* bih1 = (const float*)d_in[8];
  const float* bhh1 = (const float*)d_in[9];
  const float* Wtr  = (const float*)d_in[10];
  const float* btr  = (const float*)d_in[11];
  const float* avec = (const float*)d_in[12];
  const float* Wfc  = (const float*)d_in[13];
  const float* bfc  = (const float*)d_in[14];
  const float* Wout = (const float*)d_in[15];
  const float* bout = (const float*)d_in[16];
  float* out = (float*)d_out;

  const int N = 4000;
  char* base = (char*)d_ws;
  size_t off = 0;
  auto alloc = [&](size_t bytes) { char* p = base + off; off += (bytes + 255) & ~(size_t)255; return p; };

  float* h1a  = (float*)alloc((size_t)N * 128 * 4);
  float* h1b  = (float*)alloc((size_t)N * 128 * 4);
  unsigned short* w0f  = (unsigned short*)alloc((size_t)16 * 9 * 2 * 512 * 2);
  unsigned short* w1f  = (unsigned short*)alloc((size_t)16 * 16 * 2 * 512 * 2);
  float* biasP = (float*)alloc(1024 * 4);
  float* ssrc = (float*)alloc(N * 4);
  float* sdst = (float*)alloc(N * 4);
  float* uv   = (float*)alloc(272 * 4);
  float* part = (float*)alloc(4096 * 4);
  float* csum = (float*)alloc(128 * 4);
  int* deg    = (int*)alloc((size_t)N * 4);
  int* eidx   = (int*)alloc((size_t)N * EC * 4);

  hipLaunchKernelGGL(pack_w, dim3(288), dim3(256), 0, stream, Wih0, Whh0, 16, 9, w0f);
  hipLaunchKernelGGL(pack_w, dim3(512), dim3(256), 0, stream, Wih1, Whh1, 128, 16, w1f);
  hipLaunchKernelGGL(pack_bias, dim3(4), dim3(256), 0, stream, bih0, bhh0, bih1, bhh1, biasP);
  hipLaunchKernelGGL(build_csr, dim3(N), dim3(256), 0, stream, adj, deg, eidx, N);

  NArgs na;
  na.w0f = w0f; na.w1f = w1f; na.x = x; na.biasP = biasP; na.h1f32 = h1a;
  hipLaunchKernelGGL(lstm_node, dim3(125), dim3(512), 0, stream, na);

  hipLaunchKernelGGL(attn_prep, dim3(1), dim3(128), 0, stream, Wtr, btr, avec, uv);
  for (int r = 0; r < 2; r++) {
    const float* hid = r ? h1b : h1a;
    float* hnew = r ? h1a : h1b;
    hipLaunchKernelGGL(attn_scores, dim3(1000), dim3(256), 0, stream, hid, uv, ssrc, sdst, N);
    hipLaunchKernelGGL(colsum_part, dim3(32), dim3(128), 0, stream, hid, part, N);
    hipLaunchKernelGGL(colsum_fold, dim3(1), dim3(128), 0, stream, part, csum);
    hipLaunchKernelGGL(attn_apply, dim3(N), dim3(256), 0, stream, deg, eidx, adj, ssrc, sdst, hid, csum, hnew, N);
  }
  hipLaunchKernelGGL(head_kernel, dim3(125), dim3(256), 0, stream, h1a, Wfc, bfc, Wout, bout, out, N);
}